// Round 18
// baseline (25.781 us; speedup 1.0000x reference)
//
#include <hip/hip_runtime.h>
#include <hip/hip_bf16.h>

#define B_   32
#define N_   128
#define AH_  512
#define AW_  512
#define LCAP 64    // per-chunk list capacity (one 64-box ballot chunk)
#define LN2  0.69314718055994530942f

// compiler-only reordering fence; one wave's DS ops execute in issue order
#define CFENCE() asm volatile("" ::: "memory")

typedef __fp16 h2_t __attribute__((ext_vector_type(2)));   // matches cvt_pkrtz
union f_h2 { float f; h2_t h; };

// ---------------------------------------------------------------------------
// R18 = R17 (24.4us) with 8 ROWS PER WAVE (was 4), same amortization lever
// that won R17 (-2.6us): fixed per-wave cost serves 2x rows; band-box pairs
// halve again (box spans ~65 rows -> boxes/band ~15 at any band height).
//
// Enabling fact: the row-coverage bitmask ab is a CONTIGUOUS run (y-interval),
// and rv != 1 only at the first (r1) and last (r2) covered rows -- interior
// rows have y != y1 and y != y2-1, so rv = 1. Hence one float4 record:
//   {x1 | x2<<10 | ab<<20,  f16x2(x1m,x2m),  rv(r1),  rv(r2)}
// and the ab==255 fast path writes 8 rows/x-iter as {v1*e, e*6, v2*e}.
//
// LDS 34KB/block -> 4 blocks/CU x 2 waves; 1024 blocks all co-resident
// (2 waves/SIMD -- this round tests how much latency hiding we truly need).
// Kept verbatim: att-loads-FIRST, 2 independent waves/block, no barriers,
// ballot compaction in index order, 1-deep prefetch, scalar span bounds +
// clamp loop, ungated log2 BCE, shuffle tail.
// ---------------------------------------------------------------------------
__global__ __launch_bounds__(128) void row_bce_kernel(
    const float* __restrict__ att,
    const float* __restrict__ bboxs,
    const int*   __restrict__ img_h_p,
    const int*   __restrict__ img_w_p,
    float*       __restrict__ wave_sums)
{
    const int t    = threadIdx.x;
    const int lane = t & 63;
    const int wid  = t >> 6;                    // 0..1
    const int task = (blockIdx.x << 1) | wid;   // 0..2047
    const int b    = task >> 6;                 // 64 tasks per image
    const int y0   = (task & 63) << 3;          // rows y0..y0+7

    __shared__ float4 s_geo[2][LCAP];           // packed one-float4 records
    __shared__ float  s_mask[2][8][AW_];        // [wid][row][x]  (32 KB)

    // ---- att loads FIRST (proven ordering) ----
    const float4* p4 = (const float4*)(att + ((size_t)b * AH_ + y0) * AW_);
    float4 P[8][2];
    #pragma unroll
    for (int r = 0; r < 8; ++r)
        #pragma unroll
        for (int h = 0; h < 2; ++h)
            P[r][h] = p4[r * 128 + h * 64 + lane];

    const float fw  = (float)(*img_w_p);
    const float fh  = (float)(*img_h_p);
    const float sxs = (float)AW_ / fw;
    const float sys = (float)AH_ / fh;

    // ---- box geometry, once per wave (boxes lane and lane+64) ----
    bool   act_any[2];
    float4 rec[2];
    #pragma unroll
    for (int k = 0; k < 2; ++k) {
        const int n = lane + 64 * k;
        const float* bp = bboxs + ((size_t)b * N_ + n) * 5;
        const float c0 = bp[0], c1 = bp[1], c2 = bp[2], c3 = bp[3], lab = bp[4];
        const bool valid = (lab != -1.0f) && (c0 <= fw) && (c1 <= fh)
                                          && (c2 <= fw) && (c3 <= fh);
        const float bx1 = c0 * sxs, by1 = c1 * sys;
        const float bx2 = c2 * sxs, by2 = c3 * sys;
        const float fx1 = floorf(bx1), fy1 = floorf(by1);
        const float x1m = fx1 + 1.0f - bx1;
        const float y1m = fy1 + 1.0f - by1;
        const float x2m = bx2 - floorf(bx2);
        const float y2m = by2 - floorf(by2);
        const int x1 = (int)fmaxf(fx1, 0.0f);
        const int y1 = (int)fmaxf(fy1, 0.0f);
        const int x2 = (int)fminf(ceilf(bx2) + 1.0f, (float)AW_);
        const int y2 = (int)fminf(ceilf(by2) + 1.0f, (float)AH_);

        // covered rows within this 8-row band (contiguous run)
        const int lo = (y1 > y0) ? (y1 - y0) : 0;           // first covered r
        const int hi = ((y2 - 1) < (y0 + 7)) ? (y2 - 1 - y0) : 7;  // last r
        const bool any = valid && (lo <= hi) && (y2 > y0) && (y1 < y0 + 8)
                               && (x1 < x2);
        int ab = 0;
        if (any) ab = ((0xFF >> (7 - hi)) & (0xFF << lo)) & 0xFF;
        act_any[k] = any && (ab != 0);

        // rv at the first/last covered rows (interior rows are exactly 1.0)
        const int yA = y0 + lo, yB = y0 + hi;
        const float rvA = ((yA == y1) ? y1m : 1.0f) * ((yA == y2 - 1) ? y2m : 1.0f);
        const float rvB = ((yB == y1) ? y1m : 1.0f) * ((yB == y2 - 1) ? y2m : 1.0f);

        f_h2 u;
        u.h = __builtin_amdgcn_cvt_pkrtz(x1m, x2m);
        rec[k] = make_float4(
            __int_as_float((unsigned)x1 | ((unsigned)x2 << 10) | ((unsigned)ab << 20)),
            u.f, rvA, rvB);
    }

    const unsigned long long ltm  = (1ull << lane) - 1ull;
    const unsigned long long bal0 = __ballot(act_any[0]);
    const unsigned long long bal1 = __ballot(act_any[1]);
    const bool have = (bal0 | bal1) != 0ull;

    float* m[8];
    #pragma unroll
    for (int r = 0; r < 8; ++r) m[r] = s_mask[wid][r];
    float4* mrow4 = (float4*)m[0];

    if (have) {
        // zero all 8 mask rows: 16x ds_write_b128 per lane
        const float4 z = make_float4(0.f, 0.f, 0.f, 0.f);
        #pragma unroll
        for (int q = 0; q < 16; ++q) mrow4[lane + 64 * q] = z;
        CFENCE();

        // ---- two 64-box chunks in index order; list buffer reused ----
        #pragma unroll
        for (int k = 0; k < 2; ++k) {
            const unsigned long long bal = (k == 0) ? bal0 : bal1;
            const int cnt = __popcll(bal);
            if (cnt == 0) continue;
            if (act_any[k]) {
                const int slot = __popcll(bal & ltm);
                s_geo[wid][slot] = rec[k];      // one ds_write_b128
            }
            CFENCE();   // compaction writes precede list reads (in-order DS)

            // raster with 1-deep prefetch
            float4 g_cur = s_geo[wid][0];
            for (int j = 0; j < cnt; ++j) {
                const float4 g = g_cur;
                if (j + 1 < cnt) g_cur = s_geo[wid][j + 1];

                const unsigned pks =
                    (unsigned)__builtin_amdgcn_readfirstlane(__float_as_int(g.x));
                const int e1 = (int)(pks & 1023u);
                const int e2 = (int)((pks >> 10) & 1023u);
                const int ab = (int)(pks >> 20);
                const int r1 = __builtin_ctz(ab);          // scalar (ab != 0)
                const int r2 = 31 - __builtin_clz(ab);
                f_h2 u; u.f = g.y;
                const float x1m = (float)u.h.x;
                const float x2m = (float)u.h.y;
                const float v1  = g.z;                     // rv at r1
                const float v2  = g.w;                     // rv at r2

                const int iters = (e2 - e1 + 63) >> 6;     // scalar trip count
                if (ab == 255) {                           // full-band fast path
                    for (int q = 0; q < iters; ++q) {
                        const int xr = e1 + (q << 6) + lane;
                        const int x  = (xr < e2) ? xr : (e2 - 1);
                        const float edge = ((x == e1)     ? x1m : 1.0f)
                                         * ((x == e2 - 1) ? x2m : 1.0f);
                        const float a1 = v1 * edge;
                        const float a2 = v2 * edge;
                        m[0][x] = a1;
                        m[1][x] = edge; m[2][x] = edge; m[3][x] = edge;
                        m[4][x] = edge; m[5][x] = edge; m[6][x] = edge;
                        m[7][x] = a2;
                    }
                } else {                                   // partial band
                    for (int q = 0; q < iters; ++q) {
                        const int xr = e1 + (q << 6) + lane;
                        const int x  = (xr < e2) ? xr : (e2 - 1);
                        const float edge = ((x == e1)     ? x1m : 1.0f)
                                         * ((x == e2 - 1) ? x2m : 1.0f);
                        const float a1 = v1 * edge;
                        const float a2 = v2 * edge;
                        #pragma unroll
                        for (int r = 0; r < 8; ++r) {
                            if (ab & (1 << r)) {           // scalar-uniform guard
                                const float val = (r == r1) ? a1
                                                : ((r == r2) ? a2 : edge);
                                m[r][x] = val;
                            }
                        }
                    }
                }
            }
            CFENCE();   // raster reads precede next chunk's compaction
        }
    }

    // ---- BCE (ungated, log2 domain; p in [1e-4,1-1e-4]: no clamps) ----
    float acc = 0.0f;
    #pragma unroll
    for (int r = 0; r < 8; ++r) {
        #pragma unroll
        for (int h = 0; h < 2; ++h) {
            const float4 p = P[r][h];
            float4 mm = make_float4(0.f, 0.f, 0.f, 0.f);
            if (have) mm = mrow4[r * 128 + h * 64 + lane];
            const float pv[4] = {p.x, p.y, p.z, p.w};
            const float mv[4] = {mm.x, mm.y, mm.z, mm.w};
            #pragma unroll
            for (int j = 0; j < 4; ++j) {
                const float lp = __log2f(pv[j]);
                const float l1 = __log2f(1.0f - pv[j]);
                acc += l1 + mv[j] * (lp - l1);
            }
        }
    }
    acc *= LN2;   // one natural-log scale per wave

    // ---- wave reduction -> per-task partial ----
    #pragma unroll
    for (int off = 32; off; off >>= 1) acc += __shfl_down(acc, off, 64);
    if (lane == 0) wave_sums[task] = acc;
}

// ---------------------------------------------------------------------------
// Fused tail: per-image reduce of 64 task partials + any_valid gate +
// batch mean. One block, 1024 threads (32 workers/image); shuffle reductions.
// ---------------------------------------------------------------------------
__global__ __launch_bounds__(1024) void final_kernel(
    const float* __restrict__ bboxs,
    const int*   __restrict__ img_h_p,
    const int*   __restrict__ img_w_p,
    const float* __restrict__ wave_sums,
    float*       __restrict__ out)
{
    const int t = threadIdx.x;
    const int b = t >> 5;        // image 0..31 (two images per 64-lane wave)
    const int j = t & 31;        // worker within image

    __shared__ float s_loss[B_];

    float s = 0.0f;
    #pragma unroll
    for (int k = 0; k < 2; ++k) s += wave_sums[b * 64 + j + 32 * k];

    const float fw = (float)(*img_w_p);
    const float fh = (float)(*img_h_p);
    int av = 0;
    const float* bp = bboxs + (size_t)b * N_ * 5;
    #pragma unroll
    for (int n = j * 4; n < j * 4 + 4; ++n) {
        const float c0 = bp[n * 5 + 0];
        const float c1 = bp[n * 5 + 1];
        const float c2 = bp[n * 5 + 2];
        const float c3 = bp[n * 5 + 3];
        const float lab = bp[n * 5 + 4];
        av |= ((lab != -1.0f) && (c0 <= fw) && (c1 <= fh)
                              && (c2 <= fw) && (c3 <= fh)) ? 1 : 0;
    }

    // reduce the 32 workers of each image (half-wave groups)
    #pragma unroll
    for (int off = 16; off; off >>= 1) {
        s  += __shfl_down(s, off, 64);
        av |= __shfl_down(av, off, 64);
    }
    if (j == 0) s_loss[b] = av ? (-s * (1.0f / (float)(AH_ * AW_))) : 0.0f;
    __syncthreads();

    // batch mean: first wave, all 64 lanes live (upper 32 contribute 0)
    if (t < 64) {
        float v = (t < B_) ? s_loss[t] : 0.0f;
        #pragma unroll
        for (int off = 32; off; off >>= 1) v += __shfl_down(v, off, 64);
        if (t == 0) out[0] = v * (1.0f / (float)B_);
    }
}

extern "C" void kernel_launch(void* const* d_in, const int* in_sizes, int n_in,
                              void* d_out, int out_size, void* d_ws, size_t ws_size,
                              hipStream_t stream)
{
    const float* att   = (const float*)d_in[0];   // (32,1,512,512) f32
    const float* bboxs = (const float*)d_in[1];   // (32,128,5) f32
    const int*   img_h = (const int*)d_in[2];     // scalar
    const int*   img_w = (const int*)d_in[3];     // scalar
    float* out = (float*)d_out;
    float* wave_sums = (float*)d_ws;              // 2048 floats (8 KB)

    row_bce_kernel<<<B_ * AH_ / 16, 128, 0, stream>>>(att, bboxs, img_h, img_w, wave_sums);
    final_kernel<<<1, 1024, 0, stream>>>(bboxs, img_h, img_w, wave_sums, out);
}